// Round 1
// baseline (96636.267 us; speedup 1.0000x reference)
//
#include <hip/hip_runtime.h>
#include <math.h>

// SkipLSTM: B=128, S=512, IN=HS=1024, 4H=4096. fp32 throughout (round 0: correctness).
#define BB   128
#define SS   512
#define HSZ  1024
#define FH   4096

__device__ __forceinline__ float sigm_(float x) { return 1.0f / (1.0f + expf(-x)); }

// ---------------- tiled fp32 GEMM core: C_tile(64x64) += A(64xK=1024) @ B(1024x64) ----------------
// A: row-major, row stride lda. B: row-major, row stride 4096 (we pass base already offset to n0).
// As stored transposed [k][m] for broadcast reads; Bs [k][n].
__device__ __forceinline__ void gemm_accum(const float* __restrict__ A, long lda,
                                           const float* __restrict__ Bm,
                                           float acc[4][4],
                                           float* __restrict__ As, float* __restrict__ Bs,
                                           int tid)
{
    const int tx  = tid & 15;        // micro col group
    const int ty  = tid >> 4;        // micro row group
    const int lm  = tid >> 2;        // 0..63 : A tile row to load
    const int lk4 = (tid & 3) << 2;  // 0,4,8,12 : A k group (float4)
    const int lkB = tid >> 4;        // 0..15 : B tile k row
    const int lnB = (tid & 15) << 2; // 0..60 : B n group (float4)

    for (int k0 = 0; k0 < 1024; k0 += 16) {
        __syncthreads();   // protect LDS from previous iteration's readers
        const float4 av = *reinterpret_cast<const float4*>(A + (long)lm * lda + k0 + lk4);
        As[(lk4 + 0) * 64 + lm] = av.x;
        As[(lk4 + 1) * 64 + lm] = av.y;
        As[(lk4 + 2) * 64 + lm] = av.z;
        As[(lk4 + 3) * 64 + lm] = av.w;
        const float4 bv = *reinterpret_cast<const float4*>(Bm + (long)(k0 + lkB) * FH + lnB);
        *reinterpret_cast<float4*>(Bs + lkB * 64 + lnB) = bv;
        __syncthreads();
#pragma unroll
        for (int k = 0; k < 16; ++k) {
            const float4 a  = *reinterpret_cast<const float4*>(As + k * 64 + (ty << 2));
            const float4 bb = *reinterpret_cast<const float4*>(Bs + k * 64 + (tx << 2));
            acc[0][0] = fmaf(a.x, bb.x, acc[0][0]);
            acc[0][1] = fmaf(a.x, bb.y, acc[0][1]);
            acc[0][2] = fmaf(a.x, bb.z, acc[0][2]);
            acc[0][3] = fmaf(a.x, bb.w, acc[0][3]);
            acc[1][0] = fmaf(a.y, bb.x, acc[1][0]);
            acc[1][1] = fmaf(a.y, bb.y, acc[1][1]);
            acc[1][2] = fmaf(a.y, bb.z, acc[1][2]);
            acc[1][3] = fmaf(a.y, bb.w, acc[1][3]);
            acc[2][0] = fmaf(a.z, bb.x, acc[2][0]);
            acc[2][1] = fmaf(a.z, bb.y, acc[2][1]);
            acc[2][2] = fmaf(a.z, bb.z, acc[2][2]);
            acc[2][3] = fmaf(a.z, bb.w, acc[2][3]);
            acc[3][0] = fmaf(a.w, bb.x, acc[3][0]);
            acc[3][1] = fmaf(a.w, bb.y, acc[3][1]);
            acc[3][2] = fmaf(a.w, bb.z, acc[3][2]);
            acc[3][3] = fmaf(a.w, bb.w, acc[3][3]);
        }
    }
}

// Phase 1 (per step): blocks [0,128): A0 = b0 + x_t@U0 + h0@V0 ; blocks [128,256): T1 = h1@V1
__global__ __launch_bounds__(256)
void phase1_gemm(const float* __restrict__ xt,  const float* __restrict__ U0,
                 const float* __restrict__ h0,  const float* __restrict__ V0,
                 const float* __restrict__ b0,  float* __restrict__ A0,
                 const float* __restrict__ h1,  const float* __restrict__ V1,
                 float* __restrict__ T1)
{
    __shared__ float As[16 * 64];
    __shared__ float Bs[16 * 64];
    const int tid = threadIdx.x;
    float acc[4][4] = {};
    const bool jobB = blockIdx.x >= 128;
    const int tile = jobB ? (blockIdx.x - 128) : blockIdx.x;
    const int mt = tile & 1;           // 0..1  (M=128 / 64)
    const int nt = tile >> 1;          // 0..63 (N=4096 / 64)
    const long m0 = (long)mt * 64;
    const long n0 = (long)nt * 64;
    const int tx = tid & 15, ty = tid >> 4;

    if (!jobB) {
        gemm_accum(xt + m0 * (long)(SS * HSZ), (long)(SS * HSZ), U0 + n0, acc, As, Bs, tid);
        gemm_accum(h0 + m0 * HSZ, HSZ, V0 + n0, acc, As, Bs, tid);
#pragma unroll
        for (int i = 0; i < 4; ++i)
#pragma unroll
            for (int j = 0; j < 4; ++j) {
                const long m = m0 + (ty << 2) + i;
                const long n = n0 + (tx << 2) + j;
                A0[m * FH + n] = acc[i][j] + b0[n];
            }
    } else {
        gemm_accum(h1 + m0 * HSZ, HSZ, V1 + n0, acc, As, Bs, tid);
#pragma unroll
        for (int i = 0; i < 4; ++i)
#pragma unroll
            for (int j = 0; j < 4; ++j) {
                const long m = m0 + (ty << 2) + i;
                const long n = n0 + (tx << 2) + j;
                T1[m * FH + n] = acc[i][j];
            }
    }
}

// Phase 2 (per step): A1 = T1 + b1 + h0@U1
__global__ __launch_bounds__(256)
void phase2_gemm(const float* __restrict__ h0, const float* __restrict__ U1,
                 const float* __restrict__ T1, const float* __restrict__ b1,
                 float* __restrict__ A1)
{
    __shared__ float As[16 * 64];
    __shared__ float Bs[16 * 64];
    const int tid = threadIdx.x;
    float acc[4][4] = {};
    const int tile = blockIdx.x;
    const int mt = tile & 1;
    const int nt = tile >> 1;
    const long m0 = (long)mt * 64;
    const long n0 = (long)nt * 64;
    const int tx = tid & 15, ty = tid >> 4;

    gemm_accum(h0 + m0 * HSZ, HSZ, U1 + n0, acc, As, Bs, tid);
#pragma unroll
    for (int i = 0; i < 4; ++i)
#pragma unroll
        for (int j = 0; j < 4; ++j) {
            const long m = m0 + (ty << 2) + i;
            const long n = n0 + (tx << 2) + j;
            A1[m * FH + n] = acc[i][j] + T1[m * FH + n] + b1[n];
        }
}

// cell0 elementwise: gates from A0 -> update c0, h0 (u broadcast per batch row)
__global__ __launch_bounds__(256)
void cell0_kernel(const float* __restrict__ A0, float* __restrict__ c0,
                  float* __restrict__ h0, const float* __restrict__ u_rnd)
{
    const int idx = blockIdx.x * 256 + threadIdx.x;   // 0..131071
    const int b = idx >> 10;
    const int j = idx & 1023;
    const float* Ar = A0 + (long)b * FH;
    const float ig = sigm_(Ar[j]);
    const float fg = sigm_(Ar[HSZ + j]);
    const float gg = tanhf(Ar[2 * HSZ + j]);
    const float og = sigm_(Ar[3 * HSZ + j]);
    const float cn = fmaf(fg, c0[idx], ig * gg);
    c0[idx] = cn;
    const float u = u_rnd[b];
    h0[idx] = u * (og * tanhf(cn)) + (1.0f - u) * h0[idx];
}

// cell1 elementwise: gates from A1 -> update c1, h1; write out[b][t][:]; partial skip dot -> cum_z
__global__ __launch_bounds__(256)
void cell1_kernel(const float* __restrict__ A1, float* __restrict__ c1,
                  float* __restrict__ h1, const float* __restrict__ u_rnd,
                  const float* __restrict__ skip_w, float* __restrict__ cum_z,
                  float* __restrict__ out, int t)
{
    __shared__ float red[4];
    const int idx = blockIdx.x * 256 + threadIdx.x;   // block covers one b (1024 = 4 blocks/b)
    const int b = idx >> 10;
    const int j = idx & 1023;
    const float* Ar = A1 + (long)b * FH;
    const float ig = sigm_(Ar[j]);
    const float fg = sigm_(Ar[HSZ + j]);
    const float gg = tanhf(Ar[2 * HSZ + j]);
    const float og = sigm_(Ar[3 * HSZ + j]);
    const float cn = fmaf(fg, c1[idx], ig * gg);
    c1[idx] = cn;
    const float u = u_rnd[b];
    const float hn = u * (og * tanhf(cn)) + (1.0f - u) * h1[idx];
    h1[idx] = hn;
    out[((long)b * SS + t) * HSZ + j] = hn;

    // partial dot c1 . skip_w  (skip_w is (HS,1))
    float p = cn * skip_w[j];
#pragma unroll
    for (int off = 32; off > 0; off >>= 1) p += __shfl_down(p, off);
    const int lane = threadIdx.x & 63;
    const int w = threadIdx.x >> 6;
    if (lane == 0) red[w] = p;
    __syncthreads();
    if (threadIdx.x == 0) {
        atomicAdd(&cum_z[b], red[0] + red[1] + red[2] + red[3]);
    }
}

// per-step scalar gate recurrence (one thread per batch row)
__global__ void u_update_kernel(float* __restrict__ cum_z, float* __restrict__ u_t,
                                float* __restrict__ u_rnd, const float* __restrict__ skip_b)
{
    const int b = threadIdx.x;
    if (b >= BB) return;
    const float cu = sigm_(cum_z[b] + skip_b[0]);
    const float u  = u_rnd[b];                 // round(u_t) used this step
    const float ut = u_t[b];
    const float nut = u * cu + (1.0f - u) * (ut + fminf(cu, 1.0f - ut));
    u_t[b]   = nut;
    u_rnd[b] = rintf(nut);                     // round-half-even, matches jnp.round
    cum_z[b] = 0.0f;                           // re-zero for next step's atomics
}

// init: zero h0,c0,h1,c1,cum_z; u_t = u_rnd = 1
__global__ __launch_bounds__(256)
void init_kernel(float* __restrict__ state, float* __restrict__ cum_z,
                 float* __restrict__ u_t, float* __restrict__ u_rnd)
{
    const int idx = blockIdx.x * 256 + threadIdx.x;
    if (idx < 4 * BB * HSZ) state[idx] = 0.0f;
    if (idx < BB) { cum_z[idx] = 0.0f; u_t[idx] = 1.0f; u_rnd[idx] = 1.0f; }
}

extern "C" void kernel_launch(void* const* d_in, const int* in_sizes, int n_in,
                              void* d_out, int out_size, void* d_ws, size_t ws_size,
                              hipStream_t stream)
{
    const float* x      = (const float*)d_in[0];
    const float* U0     = (const float*)d_in[1];
    const float* V0     = (const float*)d_in[2];
    const float* b0     = (const float*)d_in[3];
    const float* U1     = (const float*)d_in[4];
    const float* V1     = (const float*)d_in[5];
    const float* b1     = (const float*)d_in[6];
    const float* skip_w = (const float*)d_in[7];
    const float* skip_b = (const float*)d_in[8];
    float* out = (float*)d_out;

    float* ws = (float*)d_ws;
    // workspace layout (floats)
    float* h0    = ws;                         // 128*1024
    float* c0    = ws + 131072;
    float* h1    = ws + 262144;
    float* c1    = ws + 393216;
    float* A0    = ws + 524288;                // 128*4096
    float* T1    = ws + 1048576;
    float* A1    = ws + 1572864;
    float* cum_z = ws + 2097152;               // 128
    float* u_t   = ws + 2097280;               // 128
    float* u_rnd = ws + 2097408;               // 128

    init_kernel<<<(4 * BB * HSZ + 255) / 256, 256, 0, stream>>>(h0, cum_z, u_t, u_rnd);

    for (int t = 0; t < SS; ++t) {
        const float* xt = x + (long)t * HSZ;   // row b at + b*S*HS
        phase1_gemm<<<256, 256, 0, stream>>>(xt, U0, h0, V0, b0, A0, h1, V1, T1);
        cell0_kernel<<<512, 256, 0, stream>>>(A0, c0, h0, u_rnd);
        phase2_gemm<<<128, 256, 0, stream>>>(h0, U1, T1, b1, A1);
        cell1_kernel<<<512, 256, 0, stream>>>(A1, c1, h1, u_rnd, skip_w, cum_z, out, t);
        u_update_kernel<<<1, 128, 0, stream>>>(cum_z, u_t, u_rnd, skip_b);
    }
}

// Round 2
// 52157.355 us; speedup vs baseline: 1.8528x; 1.8528x over previous
//
#include <hip/hip_runtime.h>
#include <math.h>

// SkipLSTM: B=128, S=512, IN=HS=1024, 4H=4096.
// Round 1: split-bf16 (hi+lo) MFMA GEMMs via v_mfma_f32_32x32x16_bf16,
// operands pre-swizzled in global memory to MFMA fragment order so staging is
// pure global_load_lds(16B). fp32-level accuracy (3-term Markidis split).
#define BB 128
#define SS 512
#define HSZ 1024
#define FH 4096

typedef __attribute__((ext_vector_type(8))) short short8;
typedef __attribute__((ext_vector_type(8))) unsigned short ushort8;
typedef __attribute__((ext_vector_type(16))) float f32x16;

#define APL 131072L   // A-plane elems (128x1024) per bf16 plane
#define BPL 4194304L  // B-plane elems (1024x4096) per bf16 plane

__device__ __forceinline__ unsigned short f2bf(float f) {
    unsigned u = __float_as_uint(f);
    u += 0x7FFFu + ((u >> 16) & 1u);
    return (unsigned short)(u >> 16);
}
__device__ __forceinline__ float bf2f(unsigned short h) {
    return __uint_as_float(((unsigned)h) << 16);
}
__device__ __forceinline__ float sigm_(float x) { return 1.0f / (1.0f + expf(-x)); }

__device__ __forceinline__ void gll16(const void* g, void* l) {
    __builtin_amdgcn_global_load_lds((const __attribute__((address_space(1))) unsigned int*)g,
                                     (__attribute__((address_space(3))) unsigned int*)l, 16, 0, 0);
}

// ---------------- split-bf16 MFMA GEMM core ----------------
// Block: 128 threads = 2 waves. Block tile 128(M) x 64(N). Wave w owns rows 64w..64w+63.
// A swizzled global layout: [kc(64)][rt(4)][lane(64)][j(8)]  (hi plane, then lo at +APL)
//   element: m = rt*32 + (lane&31), k = kc*16 + (lane>>5)*8 + j
// B swizzled global layout: [nt(128)][kc(64)][lane(64)][j(8)] (hi plane, lo at +BPL)
//   element: n = nt*32 + (lane&31), k = kc*16 + (lane>>5)*8 + j
// LDS per iter (K=32): A [pl(2)][c(2)][rt(4)][lane][8] = 16KB, B [pl][c][t(2)][lane][8] = 8KB.
__device__ __forceinline__ void gemm_core(const unsigned short* __restrict__ Ah,
                                          const unsigned short* __restrict__ Bh,
                                          int nt0, int nIter,
                                          f32x16 acc[2][2],
                                          unsigned short* lds,
                                          int wave, int lane)
{
    const long p = wave;  // wave0 stages hi planes, wave1 stages lo planes
    for (int i = 0; i < nIter; ++i) {
        __syncthreads();
        const unsigned short* Ab = Ah + p * APL + (long)i * 4096;
#pragma unroll
        for (int p8 = 0; p8 < 8; ++p8)
            gll16(Ab + p8 * 512 + lane * 8, lds + (int)p * 4096 + p8 * 512);
        const unsigned short* Bb = Bh + p * BPL;
#pragma unroll
        for (int t = 0; t < 2; ++t)
#pragma unroll
            for (int c = 0; c < 2; ++c)
                gll16(Bb + ((long)(nt0 + t) * 64 + 2 * i + c) * 512 + lane * 8,
                      lds + 8192 + (((int)p * 2 + c) * 2 + t) * 512);
        __syncthreads();
#pragma unroll
        for (int c = 0; c < 2; ++c) {
            short8 ahf[2], alf[2], bhf[2], blf[2];
#pragma unroll
            for (int r = 0; r < 2; ++r) {
                ahf[r] = *(const short8*)(lds + (c * 4 + 2 * wave + r) * 512 + lane * 8);
                alf[r] = *(const short8*)(lds + 4096 + (c * 4 + 2 * wave + r) * 512 + lane * 8);
            }
#pragma unroll
            for (int t = 0; t < 2; ++t) {
                bhf[t] = *(const short8*)(lds + 8192 + (c * 2 + t) * 512 + lane * 8);
                blf[t] = *(const short8*)(lds + 8192 + ((2 + c) * 2 + t) * 512 + lane * 8);
            }
#pragma unroll
            for (int r = 0; r < 2; ++r)
#pragma unroll
                for (int t = 0; t < 2; ++t) {
                    acc[r][t] = __builtin_amdgcn_mfma_f32_32x32x16_bf16(ahf[r], bhf[t], acc[r][t], 0, 0, 0);
                    acc[r][t] = __builtin_amdgcn_mfma_f32_32x32x16_bf16(ahf[r], blf[t], acc[r][t], 0, 0, 0);
                    acc[r][t] = __builtin_amdgcn_mfma_f32_32x32x16_bf16(alf[r], bhf[t], acc[r][t], 0, 0, 0);
                }
        }
    }
}

// phase1: blocks [0,64): A0 = x_t@U0 + h0@V0 ; blocks [64,128): T1 = h1@V1
__global__ __launch_bounds__(128) void phase1(
    const unsigned short* __restrict__ xsw,  const unsigned short* __restrict__ U0sw,
    const unsigned short* __restrict__ h0sw, const unsigned short* __restrict__ V0sw,
    const unsigned short* __restrict__ h1sw, const unsigned short* __restrict__ V1sw,
    float* __restrict__ A0, float* __restrict__ T1)
{
    __shared__ unsigned short lds[12288];
    const int tid = threadIdx.x, wave = tid >> 6, lane = tid & 63;
    const int nblk = blockIdx.x & 63;
    const int job  = blockIdx.x >> 6;
    const int nt0 = nblk * 2, n0 = nblk * 64;
    f32x16 acc[2][2];
#pragma unroll
    for (int r = 0; r < 2; ++r)
#pragma unroll
        for (int t = 0; t < 2; ++t)
#pragma unroll
            for (int q = 0; q < 16; ++q) acc[r][t][q] = 0.0f;
    float* C;
    if (job == 0) {
        gemm_core(xsw,  U0sw, nt0, 32, acc, lds, wave, lane);
        gemm_core(h0sw, V0sw, nt0, 32, acc, lds, wave, lane);
        C = A0;
    } else {
        gemm_core(h1sw, V1sw, nt0, 32, acc, lds, wave, lane);
        C = T1;
    }
#pragma unroll
    for (int r = 0; r < 2; ++r)
#pragma unroll
        for (int t = 0; t < 2; ++t)
#pragma unroll
            for (int q = 0; q < 16; ++q) {
                const int m = (2 * wave + r) * 32 + (q & 3) + 8 * (q >> 2) + 4 * (lane >> 5);
                const int n = n0 + t * 32 + (lane & 31);
                C[(long)m * FH + n] = acc[r][t][q];
            }
}

// phase2: A1 = h0@U1 + T1
__global__ __launch_bounds__(128) void phase2(
    const unsigned short* __restrict__ h0sw, const unsigned short* __restrict__ U1sw,
    const float* __restrict__ T1, float* __restrict__ A1)
{
    __shared__ unsigned short lds[12288];
    const int tid = threadIdx.x, wave = tid >> 6, lane = tid & 63;
    const int nblk = blockIdx.x;
    const int nt0 = nblk * 2, n0 = nblk * 64;
    f32x16 acc[2][2];
#pragma unroll
    for (int r = 0; r < 2; ++r)
#pragma unroll
        for (int t = 0; t < 2; ++t)
#pragma unroll
            for (int q = 0; q < 16; ++q) acc[r][t][q] = 0.0f;
    gemm_core(h0sw, U1sw, nt0, 32, acc, lds, wave, lane);
#pragma unroll
    for (int r = 0; r < 2; ++r)
#pragma unroll
        for (int t = 0; t < 2; ++t)
#pragma unroll
            for (int q = 0; q < 16; ++q) {
                const int m = (2 * wave + r) * 32 + (q & 3) + 8 * (q >> 2) + 4 * (lane >> 5);
                const int n = n0 + t * 32 + (lane & 31);
                const long idx = (long)m * FH + n;
                A1[idx] = acc[r][t][q] + T1[idx];
            }
}

// split one fp32 value-row chunk into swizzled hi/lo planes (A layout)
__device__ __forceinline__ void split_to_Asw(const float v[8], unsigned short* __restrict__ sw,
                                             int b, int k8)
{
    ushort8 hh, ll;
#pragma unroll
    for (int j = 0; j < 8; ++j) {
        const unsigned short h = f2bf(v[j]);
        hh[j] = h;
        ll[j] = f2bf(v[j] - bf2f(h));
    }
    const int kc = k8 >> 1, half = k8 & 1;
    const int l = half * 32 + (b & 31), rt = b >> 5;
    const long o = ((long)(kc * 4 + rt) * 64 + l) * 8;
    *(ushort8*)(sw + o) = hh;
    *(ushort8*)(sw + APL + o) = ll;
}

// cell0: gates from A0+b0 -> c0, h0 (fp32) + h0sw (split swizzled)
__global__ __launch_bounds__(256) void cell0(
    const float* __restrict__ A0, const float* __restrict__ b0,
    float* __restrict__ c0, float* __restrict__ h0,
    unsigned short* __restrict__ h0sw, const float* __restrict__ u_rnd)
{
    const int idx = blockIdx.x * 256 + threadIdx.x;   // 64 blocks: (b, k8)
    const int b = idx >> 7, k8 = idx & 127;
    const long gb = (long)b * FH + k8 * 8;
    const long sb = (long)b * HSZ + k8 * 8;
    const float u = u_rnd[b];
    float hn[8];
#pragma unroll
    for (int half = 0; half < 2; ++half) {
        const int j0 = half * 4;
        const float4 ai = *(const float4*)(A0 + gb + j0);
        const float4 af = *(const float4*)(A0 + gb + HSZ + j0);
        const float4 ag = *(const float4*)(A0 + gb + 2 * HSZ + j0);
        const float4 ao = *(const float4*)(A0 + gb + 3 * HSZ + j0);
        const float4 bi = *(const float4*)(b0 + k8 * 8 + j0);
        const float4 bf = *(const float4*)(b0 + HSZ + k8 * 8 + j0);
        const float4 bg = *(const float4*)(b0 + 2 * HSZ + k8 * 8 + j0);
        const float4 bo = *(const float4*)(b0 + 3 * HSZ + k8 * 8 + j0);
        float4 cv = *(const float4*)(c0 + sb + j0);
        const float4 hv = *(const float4*)(h0 + sb + j0);
        float4 cn, hq;
#pragma unroll
        for (int j = 0; j < 4; ++j) {
            const float I = sigm_(((const float*)&ai)[j] + ((const float*)&bi)[j]);
            const float F = sigm_(((const float*)&af)[j] + ((const float*)&bf)[j]);
            const float G = tanhf(((const float*)&ag)[j] + ((const float*)&bg)[j]);
            const float O = sigm_(((const float*)&ao)[j] + ((const float*)&bo)[j]);
            const float c = fmaf(F, ((const float*)&cv)[j], I * G);
            ((float*)&cn)[j] = c;
            const float h = u * (O * tanhf(c)) + (1.0f - u) * ((const float*)&hv)[j];
            ((float*)&hq)[j] = h;
            hn[j0 + j] = h;
        }
        *(float4*)(c0 + sb + j0) = cn;
        *(float4*)(h0 + sb + j0) = hq;
    }
    split_to_Asw(hn, h0sw, b, k8);
}

// cell1: gates from A1+b1 -> c1, h1, out, h1sw; fused skip-dot + u update; extra
// blocks swizzle x_{t+1}.
__global__ __launch_bounds__(256) void cell1(
    const float* __restrict__ A1, const float* __restrict__ b1,
    float* __restrict__ c1, float* __restrict__ h1,
    unsigned short* __restrict__ h1sw,
    float* __restrict__ u_t, float* __restrict__ u_rnd,
    const float* __restrict__ skip_w, const float* __restrict__ skip_b,
    float* __restrict__ out, int t,
    const float* __restrict__ x, unsigned short* __restrict__ xsw)
{
    __shared__ float red[4];
    if (blockIdx.x < 64) {
        const int idx = blockIdx.x * 256 + threadIdx.x;
        const int b = idx >> 7, k8 = idx & 127;
        const long gb = (long)b * FH + k8 * 8;
        const long sb = (long)b * HSZ + k8 * 8;
        const float u = u_rnd[b];
        const float ut_old = u_t[b];
        float hn[8];
        float part = 0.0f;
#pragma unroll
        for (int half = 0; half < 2; ++half) {
            const int j0 = half * 4;
            const float4 ai = *(const float4*)(A1 + gb + j0);
            const float4 af = *(const float4*)(A1 + gb + HSZ + j0);
            const float4 ag = *(const float4*)(A1 + gb + 2 * HSZ + j0);
            const float4 ao = *(const float4*)(A1 + gb + 3 * HSZ + j0);
            const float4 bi = *(const float4*)(b1 + k8 * 8 + j0);
            const float4 bf = *(const float4*)(b1 + HSZ + k8 * 8 + j0);
            const float4 bg = *(const float4*)(b1 + 2 * HSZ + k8 * 8 + j0);
            const float4 bo = *(const float4*)(b1 + 3 * HSZ + k8 * 8 + j0);
            float4 cv = *(const float4*)(c1 + sb + j0);
            const float4 hv = *(const float4*)(h1 + sb + j0);
            const float4 sw4 = *(const float4*)(skip_w + k8 * 8 + j0);
            float4 cn, hq;
#pragma unroll
            for (int j = 0; j < 4; ++j) {
                const float I = sigm_(((const float*)&ai)[j] + ((const float*)&bi)[j]);
                const float F = sigm_(((const float*)&af)[j] + ((const float*)&bf)[j]);
                const float G = tanhf(((const float*)&ag)[j] + ((const float*)&bg)[j]);
                const float O = sigm_(((const float*)&ao)[j] + ((const float*)&bo)[j]);
                const float c = fmaf(F, ((const float*)&cv)[j], I * G);
                ((float*)&cn)[j] = c;
                part = fmaf(c, ((const float*)&sw4)[j], part);
                const float h = u * (O * tanhf(c)) + (1.0f - u) * ((const float*)&hv)[j];
                ((float*)&hq)[j] = h;
                hn[j0 + j] = h;
            }
            *(float4*)(c1 + sb + j0) = cn;
            *(float4*)(h1 + sb + j0) = hq;
            *(float4*)(out + ((long)b * SS + t) * HSZ + k8 * 8 + j0) = hq;
        }
        split_to_Asw(hn, h1sw, b, k8);
        // block-local reduction: threads [0,128) = batch row 2*blk, [128,256) = 2*blk+1
#pragma unroll
        for (int off = 32; off > 0; off >>= 1) part += __shfl_down(part, off, 64);
        const int wave = threadIdx.x >> 6;
        if ((threadIdx.x & 63) == 0) red[wave] = part;
        __syncthreads();
        if (threadIdx.x == 0 || threadIdx.x == 128) {
            const int w0 = (threadIdx.x >> 6);
            const int bb = blockIdx.x * 2 + (threadIdx.x >> 7);
            const float z = red[w0] + red[w0 + 1];
            const float cu = sigm_(z + skip_b[0]);
            const float nut = u * cu + (1.0f - u) * (ut_old + fminf(cu, 1.0f - ut_old));
            u_t[bb] = nut;
            u_rnd[bb] = rintf(nut);
        }
    } else {
        // swizzle x for step t+1
        if (t + 1 >= SS) return;
        const int idx = (blockIdx.x - 64) * 256 + threadIdx.x;
        const int b = idx >> 7, k8 = idx & 127;
        const float* xr = x + ((long)b * SS + (t + 1)) * HSZ + k8 * 8;
        float v[8];
        const float4 v0 = *(const float4*)(xr);
        const float4 v1 = *(const float4*)(xr + 4);
#pragma unroll
        for (int j = 0; j < 4; ++j) { v[j] = ((const float*)&v0)[j]; v[4 + j] = ((const float*)&v1)[j]; }
        split_to_Asw(v, xsw, b, k8);
    }
}

// weight split+swizzle: one thread per (w, nt, kc, lane)
__global__ __launch_bounds__(256) void prep_w(
    const float* __restrict__ U0, const float* __restrict__ V0,
    const float* __restrict__ U1, const float* __restrict__ V1,
    unsigned short* __restrict__ U0sw, unsigned short* __restrict__ V0sw,
    unsigned short* __restrict__ U1sw, unsigned short* __restrict__ V1sw)
{
    const long gid = (long)blockIdx.x * 256 + threadIdx.x;  // 4 * 524288
    const int w = (int)(gid >> 19);
    const int r = (int)(gid & 524287);                      // nt*4096 + kc*64 + l
    const int nt = r >> 12;
    const int kc = (r >> 6) & 63;
    const int l = r & 63;
    const float* W = (w == 0) ? U0 : (w == 1) ? V0 : (w == 2) ? U1 : V1;
    unsigned short* O = (w == 0) ? U0sw : (w == 1) ? V0sw : (w == 2) ? U1sw : V1sw;
    const int n = nt * 32 + (l & 31);
    const int k0 = kc * 16 + (l >> 5) * 8;
    ushort8 hh, ll;
#pragma unroll
    for (int j = 0; j < 8; ++j) {
        const float f = W[(long)(k0 + j) * FH + n];
        const unsigned short h = f2bf(f);
        hh[j] = h;
        ll[j] = f2bf(f - bf2f(h));
    }
    const long ob = (long)r * 8;
    *(ushort8*)(O + ob) = hh;
    *(ushort8*)(O + BPL + ob) = ll;
}

// init: zero fp32 states, zero h0sw/h1sw, u=1, swizzle x_0
__global__ __launch_bounds__(256) void init_k(
    float* __restrict__ states, float* __restrict__ swz_f,
    float* __restrict__ u_t, float* __restrict__ u_rnd,
    const float* __restrict__ x, unsigned short* __restrict__ xsw)
{
    const int blk = blockIdx.x;
    const float4 z = {0.0f, 0.0f, 0.0f, 0.0f};
    if (blk < 512) {
        *(float4*)(states + ((long)blk * 256 + threadIdx.x) * 4) = z;
    } else if (blk < 768) {
        *(float4*)(swz_f + ((long)(blk - 512) * 256 + threadIdx.x) * 4) = z;
    } else {
        if (blk == 768 && threadIdx.x < 128) { u_t[threadIdx.x] = 1.0f; u_rnd[threadIdx.x] = 1.0f; }
        const int idx = (blk - 768) * 256 + threadIdx.x;
        const int b = idx >> 7, k8 = idx & 127;
        const float* xr = x + (long)b * SS * HSZ + k8 * 8;
        float v[8];
        const float4 v0 = *(const float4*)(xr);
        const float4 v1 = *(const float4*)(xr + 4);
#pragma unroll
        for (int j = 0; j < 4; ++j) { v[j] = ((const float*)&v0)[j]; v[4 + j] = ((const float*)&v1)[j]; }
        split_to_Asw(v, xsw, b, k8);
    }
}

extern "C" void kernel_launch(void* const* d_in, const int* in_sizes, int n_in,
                              void* d_out, int out_size, void* d_ws, size_t ws_size,
                              hipStream_t stream)
{
    const float* x      = (const float*)d_in[0];
    const float* U0     = (const float*)d_in[1];
    const float* V0     = (const float*)d_in[2];
    const float* b0     = (const float*)d_in[3];
    const float* U1     = (const float*)d_in[4];
    const float* V1     = (const float*)d_in[5];
    const float* b1     = (const float*)d_in[6];
    const float* skip_w = (const float*)d_in[7];
    const float* skip_b = (const float*)d_in[8];
    float* out = (float*)d_out;

    float* ws = (float*)d_ws;
    float* states = ws;                 // h0,c0,h1,c1 : 4*131072 floats
    float* h0 = ws;
    float* c0 = ws + 131072;
    float* h1 = ws + 262144;
    float* c1 = ws + 393216;
    float* A0 = ws + 524288;            // 128x4096
    float* T1 = ws + 1048576;
    float* A1 = ws + 1572864;
    float* u_t   = ws + 2097152;        // 128
    float* u_rnd = ws + 2097280;        // 128
    unsigned short* usbase = (unsigned short*)(ws + 2097664);  // 16B-aligned
    unsigned short* xsw  = usbase;                  // 2*APL ushorts
    unsigned short* h0sw = usbase + 262144;
    unsigned short* h1sw = usbase + 524288;
    unsigned short* U0sw = usbase + 786432;         // each 2*BPL ushorts
    unsigned short* V0sw = U0sw + 8388608;
    unsigned short* U1sw = V0sw + 8388608;
    unsigned short* V1sw = U1sw + 8388608;

    prep_w<<<8192, 256, 0, stream>>>(U0, V0, U1, V1, U0sw, V0sw, U1sw, V1sw);
    init_k<<<832, 256, 0, stream>>>(states, (float*)h0sw /* h0sw+h1sw = 256 blocks of f4 */,
                                    u_t, u_rnd, x, xsw);

    for (int t = 0; t < SS; ++t) {
        phase1<<<128, 128, 0, stream>>>(xsw, U0sw, h0sw, V0sw, h1sw, V1sw, A0, T1);
        cell0<<<64, 256, 0, stream>>>(A0, b0, c0, h0, h0sw, u_rnd);
        phase2<<<64, 128, 0, stream>>>(h0sw, U1sw, T1, A1);
        cell1<<<128, 256, 0, stream>>>(A1, b1, c1, h1, h1sw, u_t, u_rnd,
                                       skip_w, skip_b, out, t, x, xsw);
    }
}